// Round 8
// baseline (250.081 us; speedup 1.0000x reference)
//
#include <hip/hip_runtime.h>
#include <math.h>

#define N_GRAPHS 4096
#define LATENT 32
#define BLK 256

typedef float v2f __attribute__((ext_vector_type(2)));

// Zero the 33*N_GRAPHS-float accumulator workspace
__global__ __launch_bounds__(256) void zero_ws_kernel(float4* __restrict__ ws) {
    ws[blockIdx.x * 256 + threadIdx.x] = float4{0.f, 0.f, 0.f, 0.f};
}

// Fused: per-node attention score + exp + segmented weighted sums.
// r8: LDS tile halved via two k-phases of 16 columns (f32 kept).
// LDS = 256*17*4 + 1KB ~= 18.4KB -> 8 blocks/CU = 32 waves/CU (100% cap);
// r7 was 34.8KB -> 4 blocks/CU = 50% occupancy and latency-bound.
__global__ __launch_bounds__(BLK, 8) void attn_seg_kernel(
    const float* __restrict__ z, const int* __restrict__ batch,
    const float* __restrict__ w1, const float* __restrict__ b1,
    const float* __restrict__ w2, const float* __restrict__ b2,
    float* __restrict__ se, float* __restrict__ sez, int n)
{
    __shared__ float ezs[BLK * 17];   // [node][kk]: 16 e*z cols + e col (phase A)
    __shared__ int   gls[BLK];        // graph id per node

    const int t  = threadIdx.x;
    const int nd = blockIdx.x * BLK + t;
    const int ndL = (nd < n) ? nd : (n - 1);   // clamp; clamped rows get e=0
    const int g = batch[ndL];
    gls[t] = g;

    float zr[32];
    const float4* zp = reinterpret_cast<const float4*>(z + (size_t)ndL * LATENT);
    #pragma unroll
    for (int q = 0; q < 8; ++q) {
        float4 v4 = zp[q];
        zr[4*q+0] = v4.x; zr[4*q+1] = v4.y; zr[4*q+2] = v4.z; zr[4*q+3] = v4.w;
    }

    // alpha = tanh(z@W1 + b1) @ w2 + b2 -- 4 passes of 8 hidden units
    float alpha = b2[0];
    #pragma unroll
    for (int p = 0; p < 4; ++p) {
        v2f acc[4];
        const v2f* b1v = reinterpret_cast<const v2f*>(b1 + p*8);
        #pragma unroll
        for (int a = 0; a < 4; ++a) acc[a] = b1v[a];
        #pragma unroll
        for (int k = 0; k < LATENT; ++k) {
            const v2f zk2 = {zr[k], zr[k]};
            const v2f* wr = reinterpret_cast<const v2f*>(w1 + k*LATENT + p*8);
            #pragma unroll
            for (int a = 0; a < 4; ++a)
                acc[a] = __builtin_elementwise_fma(zk2, wr[a], acc[a]);
        }
        // tanh(x) = 1 - 2/(exp(2x)+1); +/-inf limits exact, no clamp needed
        #pragma unroll
        for (int a = 0; a < 4; ++a) {
            #pragma unroll
            for (int u = 0; u < 2; ++u) {
                float x  = (u == 0) ? acc[a].x : acc[a].y;
                float e2 = __expf(2.f * x);
                float th = 1.f - 2.f * __builtin_amdgcn_rcpf(e2 + 1.f);
                alpha = fmaf(th, w2[p*8 + a*2 + u], alpha);
            }
        }
    }
    // global-max subtraction cancels in per-graph normalization; skip it.
    const float e = (nd < n) ? __expf(alpha) : 0.f;

    float* row = ezs + t * 17;          // stride 17 (odd) -> conflict-free
    const int kk = t & 15, base = (t >> 4) * 16;

    // ---- phase A: k = 0..15 (+ e in col 16) ----
    #pragma unroll
    for (int k = 0; k < 16; ++k) row[k] = e * zr[k];
    row[16] = e;
    __syncthreads();
    {
        float acc = 0.f;
        int gc = gls[base];
        #pragma unroll
        for (int j = 0; j < 16; ++j) {
            int gn = gls[base + j];
            float val = ezs[(base + j) * 17 + kk];
            if (gn != gc) { atomicAdd(&sez[gc*LATENT + kk], acc); acc = 0.f; gc = gn; }
            acc += val;
        }
        atomicAdd(&sez[gc*LATENT + kk], acc);
    }
    if (t < 16) {   // e-column sweep, chunk = t
        const int b2_ = t * 16;
        float acc = 0.f;
        int gc = gls[b2_];
        #pragma unroll
        for (int j = 0; j < 16; ++j) {
            int gn = gls[b2_ + j];
            float val = ezs[(b2_ + j) * 17 + 16];
            if (gn != gc) { atomicAdd(&se[gc], acc); acc = 0.f; gc = gn; }
            acc += val;
        }
        atomicAdd(&se[gc], acc);
    }
    __syncthreads();   // WAR: reduce done before re-stage

    // ---- phase B: k = 16..31 ----
    #pragma unroll
    for (int k = 0; k < 16; ++k) row[k] = e * zr[16 + k];
    __syncthreads();
    {
        float acc = 0.f;
        int gc = gls[base];
        #pragma unroll
        for (int j = 0; j < 16; ++j) {
            int gn = gls[base + j];
            float val = ezs[(base + j) * 17 + kk];
            if (gn != gc) { atomicAdd(&sez[gc*LATENT + 16 + kk], acc); acc = 0.f; gc = gn; }
            acc += val;
        }
        atomicAdd(&sez[gc*LATENT + 16 + kk], acc);
    }
}

// One wave per graph: graph_z = sez/(se+1e-8); 32->128->64->1 MLP with sigmoid.
__global__ __launch_bounds__(64) void mlp_kernel(
    const float* __restrict__ se, const float* __restrict__ sez,
    const float* __restrict__ m1w, const float* __restrict__ m1b,
    const float* __restrict__ m2w, const float* __restrict__ m2b,
    const float* __restrict__ m3w, const float* __restrict__ m3b,
    float* __restrict__ out)
{
    int gidx = blockIdx.x;
    int lane = threadIdx.x;
    float inv = 1.f / (se[gidx] + 1e-8f);
    float gz = (lane < LATENT) ? sez[gidx*LATENT + lane] * inv : 0.f;

    float a0 = m1b[lane], a1 = m1b[lane + 64];
    #pragma unroll
    for (int k = 0; k < LATENT; ++k) {
        float zk = __shfl(gz, k);
        a0 = fmaf(zk, m1w[k*128 + lane], a0);
        a1 = fmaf(zk, m1w[k*128 + lane + 64], a1);
    }
    a0 = fmaxf(a0, 0.f); a1 = fmaxf(a1, 0.f);

    float b = m2b[lane];
    #pragma unroll
    for (int k = 0; k < 64; ++k) {
        float xk = __shfl(a0, k);
        b = fmaf(xk, m2w[k*64 + lane], b);
    }
    #pragma unroll
    for (int k = 0; k < 64; ++k) {
        float xk = __shfl(a1, k);
        b = fmaf(xk, m2w[(k+64)*64 + lane], b);
    }
    b = fmaxf(b, 0.f);

    float p = b * m3w[lane];
    #pragma unroll
    for (int s = 32; s >= 1; s >>= 1)
        p += __shfl_xor(p, s);
    if (lane == 0)
        out[gidx] = 1.f / (1.f + __expf(-(p + m3b[0])));
}

extern "C" void kernel_launch(void* const* d_in, const int* in_sizes, int n_in,
                              void* d_out, int out_size, void* d_ws, size_t ws_size,
                              hipStream_t stream)
{
    const float* z    = (const float*)d_in[0];
    const int*   batch= (const int*)d_in[1];
    const float* aw1  = (const float*)d_in[2];
    const float* ab1  = (const float*)d_in[3];
    const float* aw2  = (const float*)d_in[4];
    const float* ab2  = (const float*)d_in[5];
    const float* m1w  = (const float*)d_in[6];
    const float* m1b  = (const float*)d_in[7];
    const float* m2w  = (const float*)d_in[8];
    const float* m2b  = (const float*)d_in[9];
    const float* m3w  = (const float*)d_in[10];
    const float* m3b  = (const float*)d_in[11];
    float* out = (float*)d_out;

    int n = in_sizes[0] / LATENT;   // 2,000,000 nodes

    float* se  = (float*)d_ws;          // [4096]
    float* sez = se + N_GRAPHS;         // [4096][32]

    // N_GRAPHS*33 floats = 135168 floats = 33792 float4 = 132 blocks * 256
    zero_ws_kernel<<<132, 256, 0, stream>>>((float4*)d_ws);

    int blocks = (n + BLK - 1) / BLK;
    attn_seg_kernel<<<blocks, BLK, 0, stream>>>(z, batch, aw1, ab1, aw2, ab2, se, sez, n);
    mlp_kernel<<<N_GRAPHS, 64, 0, stream>>>(se, sez, m1w, m1b, m2w, m2b, m3w, m3b, out);
}

// Round 9
// 216.468 us; speedup vs baseline: 1.1553x; 1.1553x over previous
//
#include <hip/hip_runtime.h>
#include <math.h>

#define N_GRAPHS 4096
#define LATENT 32
#define BLK 256

typedef float v2f __attribute__((ext_vector_type(2)));

// Zero the 33*N_GRAPHS-float accumulator workspace
__global__ __launch_bounds__(256) void zero_ws_kernel(float4* __restrict__ ws) {
    ws[blockIdx.x * 256 + threadIdx.x] = float4{0.f, 0.f, 0.f, 0.f};
}

// Fused: per-node attention score + exp + segmented weighted sums.
// r9: r8's two-phase 17-col LDS tile (8 blocks/CU) + cross-chunk combine in
// LDS before global atomics. r8's counters showed 4.1M device atomics cost
// 64B EA traffic EACH WAY (FETCH +245MB / WRITE +261MB) and dominated time;
// combining 16 chunk-partials per column per block cuts atomics ~8x.
__global__ __launch_bounds__(BLK, 8) void attn_seg_kernel(
    const float* __restrict__ z, const int* __restrict__ batch,
    const float* __restrict__ w1, const float* __restrict__ b1,
    const float* __restrict__ w2, const float* __restrict__ b2,
    float* __restrict__ se, float* __restrict__ sez, int n)
{
    __shared__ float ezs[BLK * 17];   // [node][col]: 16 e*z cols (+ e col in phase A)
    __shared__ int   gls[BLK];        // graph id per node
    __shared__ float part[16 * 17];   // chunk-final partials [chunk][col]
    __shared__ int   gfin[16];        // chunk-final graph id

    const int t  = threadIdx.x;
    const int nd = blockIdx.x * BLK + t;
    const int ndL = (nd < n) ? nd : (n - 1);   // clamp; clamped rows get e=0
    const int g = batch[ndL];
    gls[t] = g;

    float zr[32];
    const float4* zp = reinterpret_cast<const float4*>(z + (size_t)ndL * LATENT);
    #pragma unroll
    for (int q = 0; q < 8; ++q) {
        float4 v4 = zp[q];
        zr[4*q+0] = v4.x; zr[4*q+1] = v4.y; zr[4*q+2] = v4.z; zr[4*q+3] = v4.w;
    }

    // alpha = tanh(z@W1 + b1) @ w2 + b2 -- 4 passes of 8 hidden units
    float alpha = b2[0];
    #pragma unroll
    for (int p = 0; p < 4; ++p) {
        v2f acc[4];
        const v2f* b1v = reinterpret_cast<const v2f*>(b1 + p*8);
        #pragma unroll
        for (int a = 0; a < 4; ++a) acc[a] = b1v[a];
        #pragma unroll
        for (int k = 0; k < LATENT; ++k) {
            const v2f zk2 = {zr[k], zr[k]};
            const v2f* wr = reinterpret_cast<const v2f*>(w1 + k*LATENT + p*8);
            #pragma unroll
            for (int a = 0; a < 4; ++a)
                acc[a] = __builtin_elementwise_fma(zk2, wr[a], acc[a]);
        }
        // tanh(x) = 1 - 2/(exp(2x)+1); +/-inf limits exact, no clamp needed
        #pragma unroll
        for (int a = 0; a < 4; ++a) {
            #pragma unroll
            for (int u = 0; u < 2; ++u) {
                float x  = (u == 0) ? acc[a].x : acc[a].y;
                float e2 = __expf(2.f * x);
                float th = 1.f - 2.f * __builtin_amdgcn_rcpf(e2 + 1.f);
                alpha = fmaf(th, w2[p*8 + a*2 + u], alpha);
            }
        }
    }
    // global-max subtraction cancels in per-graph normalization; skip it.
    const float e = (nd < n) ? __expf(alpha) : 0.f;

    float* row = ezs + t * 17;          // stride 17 (odd) -> conflict-light
    const int kk = t & 15, c = t >> 4;  // column, chunk (16 chunks x 16 nodes)
    const int base = c * 16;

    // ================= phase A: z cols 0..15, e in col 16 =================
    #pragma unroll
    for (int k = 0; k < 16; ++k) row[k] = e * zr[k];
    row[16] = e;
    if (t < 16) gfin[t] = gls[t * 16 + 15];
    __syncthreads();

    {   // per-chunk column sweep; mid-chunk boundary flushes are rare atomics
        float acc = 0.f;
        int gc = gls[base];
        #pragma unroll
        for (int j = 0; j < 16; ++j) {
            int gn = gls[base + j];
            float val = ezs[(base + j) * 17 + kk];
            if (gn != gc) { atomicAdd(&sez[gc*LATENT + kk], acc); acc = 0.f; gc = gn; }
            acc += val;
        }
        part[c * 17 + kk] = acc;        // chunk-final -> LDS, combined below
    }
    if (t < 16) {   // e-column sweep for chunk t
        const int b0 = t * 16;
        float acc = 0.f;
        int gc = gls[b0];
        #pragma unroll
        for (int j = 0; j < 16; ++j) {
            int gn = gls[b0 + j];
            float val = ezs[(b0 + j) * 17 + 16];
            if (gn != gc) { atomicAdd(&se[gc], acc); acc = 0.f; gc = gn; }
            acc += val;
        }
        part[t * 17 + 16] = acc;
    }
    __syncthreads();

    // combine 16 chunk partials per column -> ~1 atomic per column per block
    if (t < 17) {
        const int col = t;              // 16 = e column
        float acc = part[col];          // chunk 0
        int gc = gfin[0];
        #pragma unroll
        for (int cc = 1; cc < 16; ++cc) {
            int gn = gfin[cc];
            if (gn != gc) {
                if (col < 16) atomicAdd(&sez[gc*LATENT + col], acc);
                else          atomicAdd(&se[gc], acc);
                acc = 0.f; gc = gn;
            }
            acc += part[cc * 17 + col];
        }
        if (col < 16) atomicAdd(&sez[gc*LATENT + col], acc);
        else          atomicAdd(&se[gc], acc);
    }
    __syncthreads();   // WAR: all reads of ezs/part done before re-stage

    // ================= phase B: z cols 16..31 =================
    #pragma unroll
    for (int k = 0; k < 16; ++k) row[k] = e * zr[16 + k];
    __syncthreads();

    {
        float acc = 0.f;
        int gc = gls[base];
        #pragma unroll
        for (int j = 0; j < 16; ++j) {
            int gn = gls[base + j];
            float val = ezs[(base + j) * 17 + kk];
            if (gn != gc) { atomicAdd(&sez[gc*LATENT + 16 + kk], acc); acc = 0.f; gc = gn; }
            acc += val;
        }
        part[c * 17 + kk] = acc;
    }
    __syncthreads();

    if (t < 16) {
        const int col = t;
        float acc = part[col];
        int gc = gfin[0];
        #pragma unroll
        for (int cc = 1; cc < 16; ++cc) {
            int gn = gfin[cc];
            if (gn != gc) { atomicAdd(&sez[gc*LATENT + 16 + col], acc); acc = 0.f; gc = gn; }
            acc += part[cc * 17 + col];
        }
        atomicAdd(&sez[gc*LATENT + 16 + col], acc);
    }
}

// One wave per graph: graph_z = sez/(se+1e-8); 32->128->64->1 MLP with sigmoid.
__global__ __launch_bounds__(64) void mlp_kernel(
    const float* __restrict__ se, const float* __restrict__ sez,
    const float* __restrict__ m1w, const float* __restrict__ m1b,
    const float* __restrict__ m2w, const float* __restrict__ m2b,
    const float* __restrict__ m3w, const float* __restrict__ m3b,
    float* __restrict__ out)
{
    int gidx = blockIdx.x;
    int lane = threadIdx.x;
    float inv = 1.f / (se[gidx] + 1e-8f);
    float gz = (lane < LATENT) ? sez[gidx*LATENT + lane] * inv : 0.f;

    float a0 = m1b[lane], a1 = m1b[lane + 64];
    #pragma unroll
    for (int k = 0; k < LATENT; ++k) {
        float zk = __shfl(gz, k);
        a0 = fmaf(zk, m1w[k*128 + lane], a0);
        a1 = fmaf(zk, m1w[k*128 + lane + 64], a1);
    }
    a0 = fmaxf(a0, 0.f); a1 = fmaxf(a1, 0.f);

    float b = m2b[lane];
    #pragma unroll
    for (int k = 0; k < 64; ++k) {
        float xk = __shfl(a0, k);
        b = fmaf(xk, m2w[k*64 + lane], b);
    }
    #pragma unroll
    for (int k = 0; k < 64; ++k) {
        float xk = __shfl(a1, k);
        b = fmaf(xk, m2w[(k+64)*64 + lane], b);
    }
    b = fmaxf(b, 0.f);

    float p = b * m3w[lane];
    #pragma unroll
    for (int s = 32; s >= 1; s >>= 1)
        p += __shfl_xor(p, s);
    if (lane == 0)
        out[gidx] = 1.f / (1.f + __expf(-(p + m3b[0])));
}

extern "C" void kernel_launch(void* const* d_in, const int* in_sizes, int n_in,
                              void* d_out, int out_size, void* d_ws, size_t ws_size,
                              hipStream_t stream)
{
    const float* z    = (const float*)d_in[0];
    const int*   batch= (const int*)d_in[1];
    const float* aw1  = (const float*)d_in[2];
    const float* ab1  = (const float*)d_in[3];
    const float* aw2  = (const float*)d_in[4];
    const float* ab2  = (const float*)d_in[5];
    const float* m1w  = (const float*)d_in[6];
    const float* m1b  = (const float*)d_in[7];
    const float* m2w  = (const float*)d_in[8];
    const float* m2b  = (const float*)d_in[9];
    const float* m3w  = (const float*)d_in[10];
    const float* m3b  = (const float*)d_in[11];
    float* out = (float*)d_out;

    int n = in_sizes[0] / LATENT;   // 2,000,000 nodes

    float* se  = (float*)d_ws;          // [4096]
    float* sez = se + N_GRAPHS;         // [4096][32]

    // N_GRAPHS*33 floats = 135168 floats = 33792 float4 = 132 blocks * 256
    zero_ws_kernel<<<132, 256, 0, stream>>>((float4*)d_ws);

    int blocks = (n + BLK - 1) / BLK;
    attn_seg_kernel<<<blocks, BLK, 0, stream>>>(z, batch, aw1, ab1, aw2, ab2, se, sez, n);
    mlp_kernel<<<N_GRAPHS, 64, 0, stream>>>(se, sez, m1w, m1b, m2w, m2b, m3w, m3b, out);
}

// Round 10
// 94.999 us; speedup vs baseline: 2.6325x; 2.2786x over previous
//
#include <hip/hip_runtime.h>
#include <math.h>

#define N_GRAPHS 4096
#define LATENT 32
#define BLK 256

typedef float v2f __attribute__((ext_vector_type(2)));

// Zero the 33*N_GRAPHS-float accumulator workspace
__global__ __launch_bounds__(256) void zero_ws_kernel(float4* __restrict__ ws) {
    ws[blockIdx.x * 256 + threadIdx.x] = float4{0.f, 0.f, 0.f, 0.f};
}

// Fused: per-node attention score + exp + segmented weighted sums.
// r10 = r7 single-phase 33-col LDS tile (launch_bounds(256,2): 128-VGPR
// budget, NO spills -- r8/r9's (BLK,8) forced a 64-reg budget and spilled
// zr[32] to scratch: +250MB FETCH/WRITE and 2x dur) + r9's cross-chunk
// combine in LDS (atomics ~264/block -> ~40/block).
__global__ __launch_bounds__(BLK, 2) void attn_seg_kernel(
    const float* __restrict__ z, const int* __restrict__ batch,
    const float* __restrict__ w1, const float* __restrict__ b1,
    const float* __restrict__ w2, const float* __restrict__ b2,
    float* __restrict__ se, float* __restrict__ sez, int n)
{
    __shared__ float ezs[BLK * 33];   // [node][col]: 32 e*z cols + e (col 32)
    __shared__ int   gls[BLK];        // graph id per node
    __shared__ float part[8 * 33];    // chunk-final partials [chunk][col]
    __shared__ int   gfin[8];         // chunk-final graph id

    const int t  = threadIdx.x;
    const int nd = blockIdx.x * BLK + t;
    const int ndL = (nd < n) ? nd : (n - 1);   // clamp; clamped rows get e=0
    const int g = batch[ndL];
    gls[t] = g;

    float zr[32];
    const float4* zp = reinterpret_cast<const float4*>(z + (size_t)ndL * LATENT);
    #pragma unroll
    for (int q = 0; q < 8; ++q) {
        float4 v4 = zp[q];
        zr[4*q+0] = v4.x; zr[4*q+1] = v4.y; zr[4*q+2] = v4.z; zr[4*q+3] = v4.w;
    }

    // alpha = tanh(z@W1 + b1) @ w2 + b2 -- 4 passes of 8 hidden units
    float alpha = b2[0];
    #pragma unroll
    for (int p = 0; p < 4; ++p) {
        v2f acc[4];
        const v2f* b1v = reinterpret_cast<const v2f*>(b1 + p*8);
        #pragma unroll
        for (int a = 0; a < 4; ++a) acc[a] = b1v[a];
        #pragma unroll
        for (int k = 0; k < LATENT; ++k) {
            const v2f zk2 = {zr[k], zr[k]};
            const v2f* wr = reinterpret_cast<const v2f*>(w1 + k*LATENT + p*8);
            #pragma unroll
            for (int a = 0; a < 4; ++a)
                acc[a] = __builtin_elementwise_fma(zk2, wr[a], acc[a]);
        }
        // tanh(x) = 1 - 2/(exp(2x)+1); +/-inf limits exact, no clamp needed
        #pragma unroll
        for (int a = 0; a < 4; ++a) {
            #pragma unroll
            for (int u = 0; u < 2; ++u) {
                float x  = (u == 0) ? acc[a].x : acc[a].y;
                float e2 = __expf(2.f * x);
                float th = 1.f - 2.f * __builtin_amdgcn_rcpf(e2 + 1.f);
                alpha = fmaf(th, w2[p*8 + a*2 + u], alpha);
            }
        }
    }
    // global-max subtraction cancels in per-graph normalization; skip it.
    const float e = (nd < n) ? __expf(alpha) : 0.f;

    // stage e*z (cols 0..31) and e (col 32); stride 33 -> conflict-free
    float* row = ezs + t * 33;
    #pragma unroll
    for (int k = 0; k < LATENT; ++k) row[k] = e * zr[k];
    row[32] = e;
    __syncthreads();

    if (t < 8) gfin[t] = gls[t * 32 + 31];

    // k-parallel segmented sweep: 8 chunks x 32 nodes; lane = column
    {
        const int k = t & 31, c = t >> 5, base = c * 32;
        float acc = 0.f;
        int gc = gls[base];
        #pragma unroll
        for (int j = 0; j < 32; ++j) {
            int gn = gls[base + j];
            float val = ezs[(base + j) * 33 + k];
            if (gn != gc) {   // rare: graph boundary inside chunk
                atomicAdd(&sez[gc*LATENT + k], acc);
                acc = 0.f; gc = gn;
            }
            acc += val;
        }
        part[c * 33 + k] = acc;          // chunk-final -> combined below
    }
    if (t < 8) {    // e-column (col 32) sweep for chunk t
        const int base = t * 32;
        float acc = 0.f;
        int gc = gls[base];
        #pragma unroll
        for (int j = 0; j < 32; ++j) {
            int gn = gls[base + j];
            float val = ezs[(base + j) * 33 + 32];
            if (gn != gc) { atomicAdd(&se[gc], acc); acc = 0.f; gc = gn; }
            acc += val;
        }
        part[t * 33 + 32] = acc;
    }
    __syncthreads();

    // combine 8 chunk partials per column -> ~1 atomic per column per block
    if (t < 33) {
        const int col = t;               // 32 = e column
        float acc = part[col];           // chunk 0
        int gc = gfin[0];
        #pragma unroll
        for (int cc = 1; cc < 8; ++cc) {
            int gn = gfin[cc];
            if (gn != gc) {
                if (col < 32) atomicAdd(&sez[gc*LATENT + col], acc);
                else          atomicAdd(&se[gc], acc);
                acc = 0.f; gc = gn;
            }
            acc += part[cc * 33 + col];
        }
        if (col < 32) atomicAdd(&sez[gc*LATENT + col], acc);
        else          atomicAdd(&se[gc], acc);
    }
}

// One wave per graph: graph_z = sez/(se+1e-8); 32->128->64->1 MLP with sigmoid.
__global__ __launch_bounds__(64) void mlp_kernel(
    const float* __restrict__ se, const float* __restrict__ sez,
    const float* __restrict__ m1w, const float* __restrict__ m1b,
    const float* __restrict__ m2w, const float* __restrict__ m2b,
    const float* __restrict__ m3w, const float* __restrict__ m3b,
    float* __restrict__ out)
{
    int gidx = blockIdx.x;
    int lane = threadIdx.x;
    float inv = 1.f / (se[gidx] + 1e-8f);
    float gz = (lane < LATENT) ? sez[gidx*LATENT + lane] * inv : 0.f;

    float a0 = m1b[lane], a1 = m1b[lane + 64];
    #pragma unroll
    for (int k = 0; k < LATENT; ++k) {
        float zk = __shfl(gz, k);
        a0 = fmaf(zk, m1w[k*128 + lane], a0);
        a1 = fmaf(zk, m1w[k*128 + lane + 64], a1);
    }
    a0 = fmaxf(a0, 0.f); a1 = fmaxf(a1, 0.f);

    float b = m2b[lane];
    #pragma unroll
    for (int k = 0; k < 64; ++k) {
        float xk = __shfl(a0, k);
        b = fmaf(xk, m2w[k*64 + lane], b);
    }
    #pragma unroll
    for (int k = 0; k < 64; ++k) {
        float xk = __shfl(a1, k);
        b = fmaf(xk, m2w[(k+64)*64 + lane], b);
    }
    b = fmaxf(b, 0.f);

    float p = b * m3w[lane];
    #pragma unroll
    for (int s = 32; s >= 1; s >>= 1)
        p += __shfl_xor(p, s);
    if (lane == 0)
        out[gidx] = 1.f / (1.f + __expf(-(p + m3b[0])));
}

extern "C" void kernel_launch(void* const* d_in, const int* in_sizes, int n_in,
                              void* d_out, int out_size, void* d_ws, size_t ws_size,
                              hipStream_t stream)
{
    const float* z    = (const float*)d_in[0];
    const int*   batch= (const int*)d_in[1];
    const float* aw1  = (const float*)d_in[2];
    const float* ab1  = (const float*)d_in[3];
    const float* aw2  = (const float*)d_in[4];
    const float* ab2  = (const float*)d_in[5];
    const float* m1w  = (const float*)d_in[6];
    const float* m1b  = (const float*)d_in[7];
    const float* m2w  = (const float*)d_in[8];
    const float* m2b  = (const float*)d_in[9];
    const float* m3w  = (const float*)d_in[10];
    const float* m3b  = (const float*)d_in[11];
    float* out = (float*)d_out;

    int n = in_sizes[0] / LATENT;   // 2,000,000 nodes

    float* se  = (float*)d_ws;          // [4096]
    float* sez = se + N_GRAPHS;         // [4096][32]

    // N_GRAPHS*33 floats = 135168 floats = 33792 float4 = 132 blocks * 256
    zero_ws_kernel<<<132, 256, 0, stream>>>((float4*)d_ws);

    int blocks = (n + BLK - 1) / BLK;
    attn_seg_kernel<<<blocks, BLK, 0, stream>>>(z, batch, aw1, ab1, aw2, ab2, se, sez, n);
    mlp_kernel<<<N_GRAPHS, 64, 0, stream>>>(se, sez, m1w, m1b, m2w, m2b, m3w, m3b, out);
}

// Round 11
// 85.184 us; speedup vs baseline: 2.9358x; 1.1152x over previous
//
#include <hip/hip_runtime.h>
#include <math.h>

#define N_GRAPHS 4096
#define LATENT 32
#define BLK 256
#define ZSTRIDE 80   // bytes per bf16 z-row: 32*2B + pad -> 16B-aligned rows

typedef short bf16x8 __attribute__((ext_vector_type(8)));
typedef float f32x4  __attribute__((ext_vector_type(4)));
typedef int   i32x4  __attribute__((ext_vector_type(4)));

// DPP row_shr accumulate; after steps 1,2,4,8 lane 15 of each 16-row holds the row sum
// (direction verified by r5's passing wave_sum64 chain: totals accumulate at high lanes)
template<int CTRL>
__device__ __forceinline__ float dpp_shr_add(float x) {
    int y = __builtin_amdgcn_update_dpp(0, __float_as_int(x), CTRL, 0xf, 0xf, false);
    return x + __int_as_float(y);
}

__device__ __forceinline__ float tanh_fast(float x) {
    // tanh(x) = 1 - 2/(exp(2x)+1); +/-inf limits exact
    float e2 = __expf(2.f * x);
    return 1.f - 2.f * __builtin_amdgcn_rcpf(e2 + 1.f);
}

__device__ __forceinline__ unsigned short f32_to_bf16(float f) {
    unsigned int u = __float_as_uint(f);
    u += 0x7fff + ((u >> 16) & 1);   // RNE
    return (unsigned short)(u >> 16);
}

__global__ __launch_bounds__(256) void zero_ws_kernel(float4* __restrict__ ws) {
    ws[blockIdx.x * 256 + threadIdx.x] = float4{0.f, 0.f, 0.f, 0.f};
}

// Fused: per-node attention score (bf16 MFMA) + exp + segmented weighted sums.
// r11: z@W1 via mfma_f32_16x16x32_bf16 (8 MFMA/wave replaces 512 v_pk_fma +
// 128 w1 s_loads). A (z) and B (W1^T) fragments are loaded with the SAME
// slot->k map (one ds_read_b128 of 8 contiguous bf16 each) -> correct product
// for ANY internal k-layout (A/B symmetric, k-pairing cancels). Verified C/D:
// col=lane&15, row=(lane>>4)*4+reg. ezs aliases the z-tile (barrier-guarded).
__global__ __launch_bounds__(BLK, 2) void attn_seg_kernel(
    const float* __restrict__ z, const int* __restrict__ batch,
    const float* __restrict__ w1, const float* __restrict__ b1,
    const float* __restrict__ w2, const float* __restrict__ b2v,
    float* __restrict__ se, float* __restrict__ sez, int n)
{
    __shared__ __align__(16) char smem[36928];
    float* ezs  = (float*)smem;                 // [256][33] f32   (phase 2)
    char*  zb   = smem;                         // [256][ZSTRIDE] bf16 rows (phase 1)
    char*  w1T  = smem + BLK * ZSTRIDE;         // [32][ZSTRIDE]  bf16 W1^T  (phase 1)
    float* tab  = (float*)(smem + 33792);       // [4][64] alpha per wave
    int*   gls  = (int*)(smem + 34816);         // [256]
    float* part = (float*)(smem + 35840);       // [8][33]
    int*   gfin = (int*)(smem + 36896);         // [8]

    const int t = threadIdx.x;
    const int lane = t & 63, w = t >> 6;
    const int mrow = lane & 15, grp = lane >> 4;
    const int nd = blockIdx.x * BLK + t;
    const int ndL = (nd < n) ? nd : (n - 1);    // clamp; clamped rows get e=0
    gls[t] = batch[ndL];

    // small per-lane gathers (128B regions, L1-hot)
    const float b1a = b1[mrow], b1b = b1[mrow + 16];
    const float w2a = w2[mrow], w2b = w2[mrow + 16];

    // ---- stage this node's z row into LDS as bf16 ----
    float zr[32];
    const float4* zp = (const float4*)(z + (size_t)ndL * LATENT);
    #pragma unroll
    for (int q = 0; q < 8; ++q) {
        float4 v4 = zp[q];
        zr[4*q+0] = v4.x; zr[4*q+1] = v4.y; zr[4*q+2] = v4.z; zr[4*q+3] = v4.w;
    }
    int zd[16];
    #pragma unroll
    for (int i = 0; i < 16; ++i)
        asm("v_cvt_pk_bf16_f32 %0, %1, %2" : "=v"(zd[i]) : "v"(zr[2*i]), "v"(zr[2*i+1]));
    #pragma unroll
    for (int q = 0; q < 4; ++q)
        *(i32x4*)(zb + t*ZSTRIDE + q*16) = i32x4{zd[4*q], zd[4*q+1], zd[4*q+2], zd[4*q+3]};

    // ---- stage W1^T as bf16: w1T[n][k], 1024 elems / 256 threads ----
    #pragma unroll
    for (int i = 0; i < 4; ++i) {
        int idx = t*4 + i, k = idx >> 5, nc = idx & 31;
        *(unsigned short*)(w1T + nc*ZSTRIDE + k*2) = f32_to_bf16(w1[k*LATENT + nc]);
    }
    __syncthreads();   // B1: z-tile + w1T visible

    // ---- MFMA: per wave, 64 nodes x 32 hidden, K=32 ----
    bf16x8 A[4];
    #pragma unroll
    for (int T = 0; T < 4; ++T)
        A[T] = *(const bf16x8*)(zb + (w*64 + T*16 + mrow)*ZSTRIDE + grp*16);
    bf16x8 Bh0 = *(const bf16x8*)(w1T + mrow*ZSTRIDE + grp*16);          // hidden 0-15
    bf16x8 Bh1 = *(const bf16x8*)(w1T + (mrow+16)*ZSTRIDE + grp*16);     // hidden 16-31

    const f32x4 c0 = {b1a, b1a, b1a, b1a};
    const f32x4 c1 = {b1b, b1b, b1b, b1b};
    float p[4][4];
    #pragma unroll
    for (int T = 0; T < 4; ++T) {
        f32x4 d0 = __builtin_amdgcn_mfma_f32_16x16x32_bf16(A[T], Bh0, c0, 0, 0, 0);
        f32x4 d1 = __builtin_amdgcn_mfma_f32_16x16x32_bf16(A[T], Bh1, c1, 0, 0, 0);
        #pragma unroll
        for (int r = 0; r < 4; ++r)
            p[T][r] = tanh_fast(d0[r]) * w2a + tanh_fast(d1[r]) * w2b;
    }
    // sum over the 16 lanes of each row-group (cols of h); total lands in lane 15 of group
    #pragma unroll
    for (int T = 0; T < 4; ++T) {
        #pragma unroll
        for (int r = 0; r < 4; ++r) {
            float v = p[T][r];
            v = dpp_shr_add<0x111>(v);
            v = dpp_shr_add<0x112>(v);
            v = dpp_shr_add<0x114>(v);
            v = dpp_shr_add<0x118>(v);
            p[T][r] = v;
        }
    }
    if (mrow == 15) {  // lane 16*grp+15 holds sums for rows grp*4+r of each tile T
        #pragma unroll
        for (int T = 0; T < 4; ++T)
            *(f32x4*)(tab + w*64 + T*16 + grp*4) = f32x4{p[T][0], p[T][1], p[T][2], p[T][3]};
    }
    __syncthreads();   // B2: alpha table visible

    // node n=lane: T=n>>4, g=(n>>2)&3, r=n&3
    float alpha = tab[w*64 + (lane>>4)*16 + ((lane>>2)&3)*4 + (lane&3)] + b2v[0];
    // global-max subtraction cancels in per-graph normalization; skip it.
    const float e = (nd < n) ? __expf(alpha) : 0.f;

    // re-read own z row (bf16) before the tile is overwritten by ezs
    i32x4 zrd[4];
    #pragma unroll
    for (int q = 0; q < 4; ++q) zrd[q] = *(const i32x4*)(zb + t*ZSTRIDE + q*16);
    __syncthreads();   // B3: all z-tile reads complete

    float* row = ezs + t * 33;
    #pragma unroll
    for (int q = 0; q < 4; ++q) {
        #pragma unroll
        for (int j = 0; j < 4; ++j) {
            int d = zrd[q][j];
            row[q*8 + 2*j]     = e * __int_as_float(d << 16);
            row[q*8 + 2*j + 1] = e * __int_as_float(d & 0xffff0000);
        }
    }
    row[32] = e;
    __syncthreads();   // B4: ezs staged

    if (t < 8) gfin[t] = gls[t * 32 + 31];

    // k-parallel segmented sweep: 8 chunks x 32 nodes; lane = column
    {
        const int k = t & 31, c = t >> 5, base = c * 32;
        float acc = 0.f;
        int gc = gls[base];
        #pragma unroll
        for (int j = 0; j < 32; ++j) {
            int gn = gls[base + j];
            float val = ezs[(base + j) * 33 + k];
            if (gn != gc) {   // rare: graph boundary inside chunk
                atomicAdd(&sez[gc*LATENT + k], acc);
                acc = 0.f; gc = gn;
            }
            acc += val;
        }
        part[c * 33 + k] = acc;
    }
    if (t < 8) {    // e-column (col 32) sweep for chunk t
        const int base = t * 32;
        float acc = 0.f;
        int gc = gls[base];
        #pragma unroll
        for (int j = 0; j < 32; ++j) {
            int gn = gls[base + j];
            float val = ezs[(base + j) * 33 + 32];
            if (gn != gc) { atomicAdd(&se[gc], acc); acc = 0.f; gc = gn; }
            acc += val;
        }
        part[t * 33 + 32] = acc;
    }
    __syncthreads();

    // combine 8 chunk partials per column -> ~1 atomic per column per block
    if (t < 33) {
        const int col = t;               // 32 = e column
        float acc = part[col];           // chunk 0
        int gc = gfin[0];
        #pragma unroll
        for (int cc = 1; cc < 8; ++cc) {
            int gn = gfin[cc];
            if (gn != gc) {
                if (col < 32) atomicAdd(&sez[gc*LATENT + col], acc);
                else          atomicAdd(&se[gc], acc);
                acc = 0.f; gc = gn;
            }
            acc += part[cc * 33 + col];
        }
        if (col < 32) atomicAdd(&sez[gc*LATENT + col], acc);
        else          atomicAdd(&se[gc], acc);
    }
}

// One wave per graph: graph_z = sez/(se+1e-8); 32->128->64->1 MLP with sigmoid.
__global__ __launch_bounds__(64) void mlp_kernel(
    const float* __restrict__ se, const float* __restrict__ sez,
    const float* __restrict__ m1w, const float* __restrict__ m1b,
    const float* __restrict__ m2w, const float* __restrict__ m2b,
    const float* __restrict__ m3w, const float* __restrict__ m3b,
    float* __restrict__ out)
{
    int gidx = blockIdx.x;
    int lane = threadIdx.x;
    float inv = 1.f / (se[gidx] + 1e-8f);
    float gz = (lane < LATENT) ? sez[gidx*LATENT + lane] * inv : 0.f;

    float a0 = m1b[lane], a1 = m1b[lane + 64];
    #pragma unroll
    for (int k = 0; k < LATENT; ++k) {
        float zk = __shfl(gz, k);
        a0 = fmaf(zk, m1w[k*128 + lane], a0);
        a1 = fmaf(zk, m1w[k*128 + lane + 64], a1);
    }
    a0 = fmaxf(a0, 0.f); a1 = fmaxf(a1, 0.f);

    float b = m2b[lane];
    #pragma unroll
    for (int k = 0; k < 64; ++k) {
        float xk = __shfl(a0, k);
        b = fmaf(xk, m2w[k*64 + lane], b);
    }
    #pragma unroll
    for (int k = 0; k < 64; ++k) {
        float xk = __shfl(a1, k);
        b = fmaf(xk, m2w[(k+64)*64 + lane], b);
    }
    b = fmaxf(b, 0.f);

    float p = b * m3w[lane];
    #pragma unroll
    for (int s = 32; s >= 1; s >>= 1)
        p += __shfl_xor(p, s);
    if (lane == 0)
        out[gidx] = 1.f / (1.f + __expf(-(p + m3b[0])));
}

extern "C" void kernel_launch(void* const* d_in, const int* in_sizes, int n_in,
                              void* d_out, int out_size, void* d_ws, size_t ws_size,
                              hipStream_t stream)
{
    const float* z    = (const float*)d_in[0];
    const int*   batch= (const int*)d_in[1];
    const float* aw1  = (const float*)d_in[2];
    const float* ab1  = (const float*)d_in[3];
    const float* aw2  = (const float*)d_in[4];
    const float* ab2  = (const float*)d_in[5];
    const float* m1w  = (const float*)d_in[6];
    const float* m1b  = (const float*)d_in[7];
    const float* m2w  = (const float*)d_in[8];
    const float* m2b  = (const float*)d_in[9];
    const float* m3w  = (const float*)d_in[10];
    const float* m3b  = (const float*)d_in[11];
    float* out = (float*)d_out;

    int n = in_sizes[0] / LATENT;   // 2,000,000 nodes

    float* se  = (float*)d_ws;          // [4096]
    float* sez = se + N_GRAPHS;         // [4096][32]

    // N_GRAPHS*33 floats = 135168 floats = 33792 float4 = 132 blocks * 256
    zero_ws_kernel<<<132, 256, 0, stream>>>((float4*)d_ws);

    int blocks = (n + BLK - 1) / BLK;
    attn_seg_kernel<<<blocks, BLK, 0, stream>>>(z, batch, aw1, ab1, aw2, ab2, se, sez, n);
    mlp_kernel<<<N_GRAPHS, 64, 0, stream>>>(se, sez, m1w, m1b, m2w, m2b, m3w, m3b, out);
}

// Round 12
// 71.823 us; speedup vs baseline: 3.4819x; 1.1860x over previous
//
#include <hip/hip_runtime.h>
#include <math.h>

#define N_GRAPHS 4096
#define LATENT 32
#define BLK 256
#define ZSTRIDE 80   // bytes per bf16 z-row: 64B data + pad (16B-aligned, conflict-light)

typedef short bf16x8 __attribute__((ext_vector_type(8)));
typedef float f32x4  __attribute__((ext_vector_type(4)));
typedef int   i32x4  __attribute__((ext_vector_type(4)));

// DPP row_shr accumulate; after steps 1,2,4,8 lane 15 of each 16-group holds the group sum
template<int CTRL>
__device__ __forceinline__ float dpp_shr_add(float x) {
    int y = __builtin_amdgcn_update_dpp(0, __float_as_int(x), CTRL, 0xf, 0xf, false);
    return x + __int_as_float(y);
}

__device__ __forceinline__ float tanh_fast(float x) {
    // tanh(x) = 1 - 2/(exp(2x)+1); +/-inf limits exact
    float e2 = __expf(2.f * x);
    return 1.f - 2.f * __builtin_amdgcn_rcpf(e2 + 1.f);
}

__device__ __forceinline__ unsigned short f32_to_bf16(float f) {
    unsigned int u = __float_as_uint(f);
    u += 0x7fff + ((u >> 16) & 1);   // RNE
    return (unsigned short)(u >> 16);
}

__global__ __launch_bounds__(256) void zero_ws_kernel(float4* __restrict__ ws) {
    ws[blockIdx.x * 256 + threadIdx.x] = float4{0.f, 0.f, 0.f, 0.f};
}

// Fused: per-node attention score (bf16 MFMA) + exp + segmented weighted sums.
// r12 vs r11: NO e*z materialization. The sweep reads the bf16 z-tile directly
// and multiplies by a broadcast e-column (ev[256]) -> removes 33 ds_writes +
// 4 ds_read_b128 + 64 unpack VALU per thread and one barrier phase. LDS
// 36.9KB -> 25.6KB (tab aliased over part, barrier-separated) -> 6 blocks/CU
// (24 waves, 75% cap) vs r11's 4 blocks.
__global__ __launch_bounds__(BLK, 2) void attn_seg_kernel(
    const float* __restrict__ z, const int* __restrict__ batch,
    const float* __restrict__ w1, const float* __restrict__ b1,
    const float* __restrict__ w2, const float* __restrict__ b2v,
    float* __restrict__ se, float* __restrict__ sez, int n)
{
    // layout (bytes):
    //     0 .. 20480  zb   [256][ZSTRIDE] bf16 z rows (lives whole kernel)
    // 20480 .. 23040  w1T  [32][ZSTRIDE]  bf16 W1^T
    // 23040 .. 24064  gls  [256] i32
    // 24064 .. 25088  ev   [256] f32
    // 25088 .. 26144  tab  [256] f32  (phase 1)  ALIASES part [8][33] (phase 2)
    // 26144 .. 26176  gfin [8] i32   (no overlap with tab)
    __shared__ __align__(16) char smem[26176];
    char*  zb   = smem;
    char*  w1T  = smem + 20480;
    int*   gls  = (int*)(smem + 23040);
    float* ev   = (float*)(smem + 24064);
    float* tab  = (float*)(smem + 25088);
    float* part = (float*)(smem + 25088);
    int*   gfin = (int*)(smem + 26144);

    const int t = threadIdx.x;
    const int lane = t & 63, w = t >> 6;
    const int mrow = lane & 15, grp = lane >> 4;
    const int nd = blockIdx.x * BLK + t;
    const int ndL = (nd < n) ? nd : (n - 1);    // clamp; clamped rows get e=0
    gls[t] = batch[ndL];

    // small per-lane gathers (128B regions, L1-hot)
    const float b1a = b1[mrow], b1b = b1[mrow + 16];
    const float w2a = w2[mrow], w2b = w2[mrow + 16];

    // ---- stage this node's z row into LDS as bf16 ----
    float zr[32];
    const float4* zp = (const float4*)(z + (size_t)ndL * LATENT);
    #pragma unroll
    for (int q = 0; q < 8; ++q) {
        float4 v4 = zp[q];
        zr[4*q+0] = v4.x; zr[4*q+1] = v4.y; zr[4*q+2] = v4.z; zr[4*q+3] = v4.w;
    }
    int zd[16];
    #pragma unroll
    for (int i = 0; i < 16; ++i)
        asm("v_cvt_pk_bf16_f32 %0, %1, %2" : "=v"(zd[i]) : "v"(zr[2*i]), "v"(zr[2*i+1]));
    #pragma unroll
    for (int q = 0; q < 4; ++q)
        *(i32x4*)(zb + t*ZSTRIDE + q*16) = i32x4{zd[4*q], zd[4*q+1], zd[4*q+2], zd[4*q+3]};

    // ---- stage W1^T as bf16: w1T[n][k], 1024 elems / 256 threads ----
    #pragma unroll
    for (int i = 0; i < 4; ++i) {
        int idx = t*4 + i, k = idx >> 5, nc = idx & 31;
        *(unsigned short*)(w1T + nc*ZSTRIDE + k*2) = f32_to_bf16(w1[k*LATENT + nc]);
    }
    __syncthreads();   // B1: z-tile + w1T + gls visible

    // ---- MFMA: per wave, 64 nodes x 32 hidden, K=32 ----
    bf16x8 A[4];
    #pragma unroll
    for (int T = 0; T < 4; ++T)
        A[T] = *(const bf16x8*)(zb + (w*64 + T*16 + mrow)*ZSTRIDE + grp*16);
    bf16x8 Bh0 = *(const bf16x8*)(w1T + mrow*ZSTRIDE + grp*16);          // hidden 0-15
    bf16x8 Bh1 = *(const bf16x8*)(w1T + (mrow+16)*ZSTRIDE + grp*16);     // hidden 16-31

    const f32x4 c0 = {b1a, b1a, b1a, b1a};
    const f32x4 c1 = {b1b, b1b, b1b, b1b};
    float p[4][4];
    #pragma unroll
    for (int T = 0; T < 4; ++T) {
        f32x4 d0 = __builtin_amdgcn_mfma_f32_16x16x32_bf16(A[T], Bh0, c0, 0, 0, 0);
        f32x4 d1 = __builtin_amdgcn_mfma_f32_16x16x32_bf16(A[T], Bh1, c1, 0, 0, 0);
        #pragma unroll
        for (int r = 0; r < 4; ++r)
            p[T][r] = tanh_fast(d0[r]) * w2a + tanh_fast(d1[r]) * w2b;
    }
    // sum the 16 lanes of each group (hidden cols); total lands in lane 15 of group
    #pragma unroll
    for (int T = 0; T < 4; ++T) {
        #pragma unroll
        for (int r = 0; r < 4; ++r) {
            float v = p[T][r];
            v = dpp_shr_add<0x111>(v);
            v = dpp_shr_add<0x112>(v);
            v = dpp_shr_add<0x114>(v);
            v = dpp_shr_add<0x118>(v);
            p[T][r] = v;
        }
    }
    if (mrow == 15) {  // lane 16*grp+15 holds sums for node-rows grp*4+r of tile T
        #pragma unroll
        for (int T = 0; T < 4; ++T)
            *(f32x4*)(tab + w*64 + T*16 + grp*4) = f32x4{p[T][0], p[T][1], p[T][2], p[T][3]};
    }
    __syncthreads();   // B2: alpha table visible

    // node n=lane: T=n>>4, g=(n>>2)&3, r=n&3
    float alpha = tab[w*64 + (lane>>4)*16 + ((lane>>2)&3)*4 + (lane&3)] + b2v[0];
    // global-max subtraction cancels in per-graph normalization; skip it.
    const float e = (nd < n) ? __expf(alpha) : 0.f;
    ev[t] = e;
    if (t < 8) gfin[t] = gls[t * 32 + 31];
    __syncthreads();   // B3: ev visible; tab reads done (part may now overwrite)

    // k-parallel segmented sweep: 8 chunks x 32 nodes; lane = z column.
    // reads bf16 z directly from the resident tile; e broadcast from ev.
    {
        const int k = t & 31, c = t >> 5, base = c * 32;
        float acc = 0.f;
        int gc = gls[base];
        #pragma unroll
        for (int j = 0; j < 32; ++j) {
            int gn = gls[base + j];
            float ej = ev[base + j];
            unsigned int hz = *(const unsigned short*)(zb + (base + j)*ZSTRIDE + k*2);
            float val = ej * __int_as_float(hz << 16);
            if (gn != gc) {   // rare: graph boundary inside chunk
                atomicAdd(&sez[gc*LATENT + k], acc);
                acc = 0.f; gc = gn;
            }
            acc += val;
        }
        part[c * 33 + k] = acc;
    }
    if (t < 8) {    // e-column sweep for chunk t
        const int base = t * 32;
        float acc = 0.f;
        int gc = gls[base];
        #pragma unroll
        for (int j = 0; j < 32; ++j) {
            int gn = gls[base + j];
            float val = ev[base + j];
            if (gn != gc) { atomicAdd(&se[gc], acc); acc = 0.f; gc = gn; }
            acc += val;
        }
        part[t * 33 + 32] = acc;
    }
    __syncthreads();   // B4: part staged

    // combine 8 chunk partials per column -> ~1 atomic per column per block
    if (t < 33) {
        const int col = t;               // 32 = e column
        float acc = part[col];           // chunk 0
        int gc = gfin[0];
        #pragma unroll
        for (int cc = 1; cc < 8; ++cc) {
            int gn = gfin[cc];
            if (gn != gc) {
                if (col < 32) atomicAdd(&sez[gc*LATENT + col], acc);
                else          atomicAdd(&se[gc], acc);
                acc = 0.f; gc = gn;
            }
            acc += part[cc * 33 + col];
        }
        if (col < 32) atomicAdd(&sez[gc*LATENT + col], acc);
        else          atomicAdd(&se[gc], acc);
    }
}

// One wave per graph: graph_z = sez/(se+1e-8); 32->128->64->1 MLP with sigmoid.
__global__ __launch_bounds__(64) void mlp_kernel(
    const float* __restrict__ se, const float* __restrict__ sez,
    const float* __restrict__ m1w, const float* __restrict__ m1b,
    const float* __restrict__ m2w, const float* __restrict__ m2b,
    const float* __restrict__ m3w, const float* __restrict__ m3b,
    float* __restrict__ out)
{
    int gidx = blockIdx.x;
    int lane = threadIdx.x;
    float inv = 1.f / (se[gidx] + 1e-8f);
    float gz = (lane < LATENT) ? sez[gidx*LATENT + lane] * inv : 0.f;

    float a0 = m1b[lane], a1 = m1b[lane + 64];
    #pragma unroll
    for (int k = 0; k < LATENT; ++k) {
        float zk = __shfl(gz, k);
        a0 = fmaf(zk, m1w[k*128 + lane], a0);
        a1 = fmaf(zk, m1w[k*128 + lane + 64], a1);
    }
    a0 = fmaxf(a0, 0.f); a1 = fmaxf(a1, 0.f);

    float b = m2b[lane];
    #pragma unroll
    for (int k = 0; k < 64; ++k) {
        float xk = __shfl(a0, k);
        b = fmaf(xk, m2w[k*64 + lane], b);
    }
    #pragma unroll
    for (int k = 0; k < 64; ++k) {
        float xk = __shfl(a1, k);
        b = fmaf(xk, m2w[(k+64)*64 + lane], b);
    }
    b = fmaxf(b, 0.f);

    float p = b * m3w[lane];
    #pragma unroll
    for (int s = 32; s >= 1; s >>= 1)
        p += __shfl_xor(p, s);
    if (lane == 0)
        out[gidx] = 1.f / (1.f + __expf(-(p + m3b[0])));
}

extern "C" void kernel_launch(void* const* d_in, const int* in_sizes, int n_in,
                              void* d_out, int out_size, void* d_ws, size_t ws_size,
                              hipStream_t stream)
{
    const float* z    = (const float*)d_in[0];
    const int*   batch= (const int*)d_in[1];
    const float* aw1  = (const float*)d_in[2];
    const float* ab1  = (const float*)d_in[3];
    const float* aw2  = (const float*)d_in[4];
    const float* ab2  = (const float*)d_in[5];
    const float* m1w  = (const float*)d_in[6];
    const float* m1b  = (const float*)d_in[7];
    const float* m2w  = (const float*)d_in[8];
    const float* m2b  = (const float*)d_in[9];
    const float* m3w  = (const float*)d_in[10];
    const float* m3b  = (const float*)d_in[11];
    float* out = (float*)d_out;

    int n = in_sizes[0] / LATENT;   // 2,000,000 nodes

    float* se  = (float*)d_ws;          // [4096]
    float* sez = se + N_GRAPHS;         // [4096][32]

    // N_GRAPHS*33 floats = 135168 floats = 33792 float4 = 132 blocks * 256
    zero_ws_kernel<<<132, 256, 0, stream>>>((float4*)d_ws);

    int blocks = (n + BLK - 1) / BLK;
    attn_seg_kernel<<<blocks, BLK, 0, stream>>>(z, batch, aw1, ab1, aw2, ab2, se, sez, n);
    mlp_kernel<<<N_GRAPHS, 64, 0, stream>>>(se, sez, m1w, m1b, m2w, m2b, m3w, m3b, out);
}

// Round 13
// 63.045 us; speedup vs baseline: 3.9667x; 1.1392x over previous
//
#include <hip/hip_runtime.h>
#include <math.h>

#define N_GRAPHS 4096
#define LATENT 32
#define BLK 256
#define ZSTRIDE 80   // bytes per bf16 z-row: 64B data + 16B pad (16B-aligned rows)

typedef short bf16x8 __attribute__((ext_vector_type(8)));
typedef float f32x4  __attribute__((ext_vector_type(4)));
typedef int   i32x4  __attribute__((ext_vector_type(4)));

// DPP row_shr accumulate; after steps 1,2,4,8 lane 15 of each 16-group holds the group sum
template<int CTRL>
__device__ __forceinline__ float dpp_shr_add(float x) {
    int y = __builtin_amdgcn_update_dpp(0, __float_as_int(x), CTRL, 0xf, 0xf, false);
    return x + __int_as_float(y);
}

__device__ __forceinline__ float tanh_fast(float x) {
    // tanh(x) = 1 - 2/(exp(2x)+1); +/-inf limits exact
    float e2 = __expf(2.f * x);
    return 1.f - 2.f * __builtin_amdgcn_rcpf(e2 + 1.f);
}

__device__ __forceinline__ unsigned short f32_to_bf16(float f) {
    unsigned int u = __float_as_uint(f);
    u += 0x7fff + ((u >> 16) & 1);   // RNE
    return (unsigned short)(u >> 16);
}

__global__ __launch_bounds__(256) void zero_ws_kernel(float4* __restrict__ ws) {
    ws[blockIdx.x * 256 + threadIdx.x] = float4{0.f, 0.f, 0.f, 0.f};
}

// Fused: per-node attention score (bf16 MFMA) + exp + segmented weighted sums.
// r13 vs r12: register-batched sweep. r12's sweep issued 96 LDS reads/thread
// (32 z u16 + 32 ev + 32 gls); now 16 chunks x 16 nodes, thread (c,kk) handles
// col pair (2kk,2kk+1) with one b32 z-read per node, and e/g for the whole
// chunk live in registers (8 broadcast b128 loads). kk==0 lane sweeps the
// e-column from the same registers: 96 -> ~26 LDS ops/thread.
__global__ __launch_bounds__(BLK, 2) void attn_seg_kernel(
    const float* __restrict__ z, const int* __restrict__ batch,
    const float* __restrict__ w1, const float* __restrict__ b1,
    const float* __restrict__ w2, const float* __restrict__ b2v,
    float* __restrict__ se, float* __restrict__ sez, int n)
{
    // layout (bytes):
    //     0 .. 20480  zb   [256][ZSTRIDE] bf16 z rows (lives whole kernel)
    // 20480 .. 21504  gls  [256] i32
    // 21504 .. 22528  ev   [256] f32
    // 22528 .. 25088  w1T  [32][ZSTRIDE] bf16 (dead after MFMA)
    //                      ALIASED by part [16][36] f32 (phase 2; col 32 = e,
    //                      col 33 = gfin as int bits; 2304B)
    // 25088 .. 26112  tab  [256] f32 (dead after alpha read)
    __shared__ __align__(16) char smem[26112];
    char*  zb   = smem;
    int*   gls  = (int*)(smem + 20480);
    float* ev   = (float*)(smem + 21504);
    char*  w1T  = smem + 22528;
    float* part = (float*)(smem + 22528);
    float* tab  = (float*)(smem + 25088);

    const int t = threadIdx.x;
    const int lane = t & 63, w = t >> 6;
    const int mrow = lane & 15, grp = lane >> 4;
    const int nd = blockIdx.x * BLK + t;
    const int ndL = (nd < n) ? nd : (n - 1);    // clamp; clamped rows get e=0
    gls[t] = batch[ndL];

    // small per-lane gathers (128B regions, L1-hot)
    const float b1a = b1[mrow], b1b = b1[mrow + 16];
    const float w2a = w2[mrow], w2b = w2[mrow + 16];

    // ---- stage this node's z row into LDS as bf16 ----
    float zr[32];
    const float4* zp = (const float4*)(z + (size_t)ndL * LATENT);
    #pragma unroll
    for (int q = 0; q < 8; ++q) {
        float4 v4 = zp[q];
        zr[4*q+0] = v4.x; zr[4*q+1] = v4.y; zr[4*q+2] = v4.z; zr[4*q+3] = v4.w;
    }
    int zd[16];
    #pragma unroll
    for (int i = 0; i < 16; ++i)
        asm("v_cvt_pk_bf16_f32 %0, %1, %2" : "=v"(zd[i]) : "v"(zr[2*i]), "v"(zr[2*i+1]));
    #pragma unroll
    for (int q = 0; q < 4; ++q)
        *(i32x4*)(zb + t*ZSTRIDE + q*16) = i32x4{zd[4*q], zd[4*q+1], zd[4*q+2], zd[4*q+3]};

    // ---- stage W1^T as bf16: w1T[n][k], 1024 elems / 256 threads ----
    #pragma unroll
    for (int i = 0; i < 4; ++i) {
        int idx = t*4 + i, k = idx >> 5, nc = idx & 31;
        *(unsigned short*)(w1T + nc*ZSTRIDE + k*2) = f32_to_bf16(w1[k*LATENT + nc]);
    }
    __syncthreads();   // B1: z-tile + w1T + gls visible

    // ---- MFMA: per wave, 64 nodes x 32 hidden, K=32 ----
    bf16x8 A[4];
    #pragma unroll
    for (int T = 0; T < 4; ++T)
        A[T] = *(const bf16x8*)(zb + (w*64 + T*16 + mrow)*ZSTRIDE + grp*16);
    bf16x8 Bh0 = *(const bf16x8*)(w1T + mrow*ZSTRIDE + grp*16);          // hidden 0-15
    bf16x8 Bh1 = *(const bf16x8*)(w1T + (mrow+16)*ZSTRIDE + grp*16);     // hidden 16-31

    const f32x4 c0 = {b1a, b1a, b1a, b1a};
    const f32x4 c1 = {b1b, b1b, b1b, b1b};
    float p[4][4];
    #pragma unroll
    for (int T = 0; T < 4; ++T) {
        f32x4 d0 = __builtin_amdgcn_mfma_f32_16x16x32_bf16(A[T], Bh0, c0, 0, 0, 0);
        f32x4 d1 = __builtin_amdgcn_mfma_f32_16x16x32_bf16(A[T], Bh1, c1, 0, 0, 0);
        #pragma unroll
        for (int r = 0; r < 4; ++r)
            p[T][r] = tanh_fast(d0[r]) * w2a + tanh_fast(d1[r]) * w2b;
    }
    // sum the 16 lanes of each group (hidden cols); total lands in lane 15 of group
    #pragma unroll
    for (int T = 0; T < 4; ++T) {
        #pragma unroll
        for (int r = 0; r < 4; ++r) {
            float v = p[T][r];
            v = dpp_shr_add<0x111>(v);
            v = dpp_shr_add<0x112>(v);
            v = dpp_shr_add<0x114>(v);
            v = dpp_shr_add<0x118>(v);
            p[T][r] = v;
        }
    }
    if (mrow == 15) {  // lane 16*grp+15 holds sums for node-rows grp*4+r of tile T
        #pragma unroll
        for (int T = 0; T < 4; ++T)
            *(f32x4*)(tab + w*64 + T*16 + grp*4) = f32x4{p[T][0], p[T][1], p[T][2], p[T][3]};
    }
    __syncthreads();   // B2: alpha table visible

    // node n=lane: T=n>>4, g=(n>>2)&3, r=n&3
    float alpha = tab[w*64 + (lane>>4)*16 + ((lane>>2)&3)*4 + (lane&3)] + b2v[0];
    // global-max subtraction cancels in per-graph normalization; skip it.
    const float e = (nd < n) ? __expf(alpha) : 0.f;
    ev[t] = e;
    __syncthreads();   // B3: ev visible; w1T/tab reads done (part may overwrite)

    // register-batched segmented sweep: 16 chunks x 16 nodes.
    // thread (c = t>>4, kk = t&15) sums columns 2kk, 2kk+1 over its chunk.
    {
        const int c  = t >> 4;
        const int kk = t & 15;
        const int base = c * 16;
        const f32x4 e0 = *(const f32x4*)(ev + base);
        const f32x4 e1 = *(const f32x4*)(ev + base + 4);
        const f32x4 e2 = *(const f32x4*)(ev + base + 8);
        const f32x4 e3 = *(const f32x4*)(ev + base + 12);
        const i32x4 g0 = *(const i32x4*)(gls + base);
        const i32x4 g1 = *(const i32x4*)(gls + base + 4);
        const i32x4 g2 = *(const i32x4*)(gls + base + 8);
        const i32x4 g3 = *(const i32x4*)(gls + base + 12);

        float a0 = 0.f, a1 = 0.f;
        int gc = g0[0];
        #pragma unroll
        for (int j = 0; j < 16; ++j) {
            const int   gn = (j < 4) ? g0[j&3] : (j < 8) ? g1[j&3] : (j < 12) ? g2[j&3] : g3[j&3];
            const float ej = (j < 4) ? e0[j&3] : (j < 8) ? e1[j&3] : (j < 12) ? e2[j&3] : e3[j&3];
            const int d = *(const int*)(zb + (base + j)*ZSTRIDE + kk*4);
            if (gn != gc) {   // rare: graph boundary inside chunk
                atomicAdd(&sez[gc*LATENT + 2*kk],     a0);
                atomicAdd(&sez[gc*LATENT + 2*kk + 1], a1);
                a0 = a1 = 0.f; gc = gn;
            }
            a0 = fmaf(ej, __int_as_float((unsigned)d << 16),        a0);
            a1 = fmaf(ej, __int_as_float((unsigned)d & 0xffff0000u), a1);
        }
        *(float2*)(part + c*36 + 2*kk) = float2{a0, a1};

        if (kk == 0) {   // e-column sweep for chunk c, straight from registers
            float ae = 0.f;
            int ge = g0[0];
            #pragma unroll
            for (int j = 0; j < 16; ++j) {
                const int   gn = (j < 4) ? g0[j&3] : (j < 8) ? g1[j&3] : (j < 12) ? g2[j&3] : g3[j&3];
                const float ej = (j < 4) ? e0[j&3] : (j < 8) ? e1[j&3] : (j < 12) ? e2[j&3] : e3[j&3];
                if (gn != ge) { atomicAdd(&se[ge], ae); ae = 0.f; ge = gn; }
                ae += ej;
            }
            part[c*36 + 32] = ae;
            ((int*)part)[c*36 + 33] = g3[3];   // chunk-final graph id
        }
    }
    __syncthreads();   // B4: part staged

    // combine 16 chunk partials per column -> ~1 atomic per column per block
    if (t < 33) {
        const int col = t;               // 32 = e column
        float acc = part[col];           // chunk 0
        int gc = ((const int*)part)[33];
        #pragma unroll
        for (int cc = 1; cc < 16; ++cc) {
            const int gn = ((const int*)part)[cc*36 + 33];
            if (gn != gc) {
                if (col < 32) atomicAdd(&sez[gc*LATENT + col], acc);
                else          atomicAdd(&se[gc], acc);
                acc = 0.f; gc = gn;
            }
            acc += part[cc*36 + col];
        }
        if (col < 32) atomicAdd(&sez[gc*LATENT + col], acc);
        else          atomicAdd(&se[gc], acc);
    }
}

// One wave per graph: graph_z = sez/(se+1e-8); 32->128->64->1 MLP with sigmoid.
__global__ __launch_bounds__(64) void mlp_kernel(
    const float* __restrict__ se, const float* __restrict__ sez,
    const float* __restrict__ m1w, const float* __restrict__ m1b,
    const float* __restrict__ m2w, const float* __restrict__ m2b,
    const float* __restrict__ m3w, const float* __restrict__ m3b,
    float* __restrict__ out)
{
    int gidx = blockIdx.x;
    int lane = threadIdx.x;
    float inv = 1.f / (se[gidx] + 1e-8f);
    float gz = (lane < LATENT) ? sez[gidx*LATENT + lane] * inv : 0.f;

    float a0 = m1b[lane], a1 = m1b[lane + 64];
    #pragma unroll
    for (int k = 0; k < LATENT; ++k) {
        float zk = __shfl(gz, k);
        a0 = fmaf(zk, m1w[k*128 + lane], a0);
        a1 = fmaf(zk, m1w[k*128 + lane + 64], a1);
    }
    a0 = fmaxf(a0, 0.f); a1 = fmaxf(a1, 0.f);

    float b = m2b[lane];
    #pragma unroll
    for (int k = 0; k < 64; ++k) {
        float xk = __shfl(a0, k);
        b = fmaf(xk, m2w[k*64 + lane], b);
    }
    #pragma unroll
    for (int k = 0; k < 64; ++k) {
        float xk = __shfl(a1, k);
        b = fmaf(xk, m2w[(k+64)*64 + lane], b);
    }
    b = fmaxf(b, 0.f);

    float p = b * m3w[lane];
    #pragma unroll
    for (int s = 32; s >= 1; s >>= 1)
        p += __shfl_xor(p, s);
    if (lane == 0)
        out[gidx] = 1.f / (1.f + __expf(-(p + m3b[0])));
}

extern "C" void kernel_launch(void* const* d_in, const int* in_sizes, int n_in,
                              void* d_out, int out_size, void* d_ws, size_t ws_size,
                              hipStream_t stream)
{
    const float* z    = (const float*)d_in[0];
    const int*   batch= (const int*)d_in[1];
    const float* aw1  = (const float*)d_in[2];
    const float* ab1  = (const float*)d_in[3];
    const float* aw2  = (const float*)d_in[4];
    const float* ab2  = (const float*)d_in[5];
    const float* m1w  = (const float*)d_in[6];
    const float* m1b  = (const float*)d_in[7];
    const float* m2w  = (const float*)d_in[8];
    const float* m2b  = (const float*)d_in[9];
    const float* m3w  = (const float*)d_in[10];
    const float* m3b  = (const float*)d_in[11];
    float* out = (float*)d_out;

    int n = in_sizes[0] / LATENT;   // 2,000,000 nodes

    float* se  = (float*)d_ws;          // [4096]
    float* sez = se + N_GRAPHS;         // [4096][32]

    // N_GRAPHS*33 floats = 135168 floats = 33792 float4 = 132 blocks * 256
    zero_ws_kernel<<<132, 256, 0, stream>>>((float4*)d_ws);

    int blocks = (n + BLK - 1) / BLK;
    attn_seg_kernel<<<blocks, BLK, 0, stream>>>(z, batch, aw1, ab1, aw2, ab2, se, sez, n);
    mlp_kernel<<<N_GRAPHS, 64, 0, stream>>>(se, sez, m1w, m1b, m2w, m2b, m3w, m3b, out);
}

// Round 14
// 62.301 us; speedup vs baseline: 4.0141x; 1.0119x over previous
//
#include <hip/hip_runtime.h>
#include <math.h>

#define N_GRAPHS 4096
#define LATENT 32
#define BLK 256
#define ZSTRIDE 80   // bytes per bf16 z-row: 64B data + 16B pad (16B-aligned rows)

typedef short bf16x8 __attribute__((ext_vector_type(8)));
typedef float f32x4  __attribute__((ext_vector_type(4)));
typedef int   i32x4  __attribute__((ext_vector_type(4)));

// DPP row_shr accumulate; after steps 1,2,4,8 lane 15 of each 16-group holds the group sum
template<int CTRL>
__device__ __forceinline__ float dpp_shr_add(float x) {
    int y = __builtin_amdgcn_update_dpp(0, __float_as_int(x), CTRL, 0xf, 0xf, false);
    return x + __int_as_float(y);
}

__device__ __forceinline__ float tanh_fast(float x) {
    // tanh(x) = 1 - 2/(exp(2x)+1); +/-inf limits exact
    float e2 = __expf(2.f * x);
    return 1.f - 2.f * __builtin_amdgcn_rcpf(e2 + 1.f);
}

__device__ __forceinline__ unsigned short f32_to_bf16(float f) {
    unsigned int u = __float_as_uint(f);
    u += 0x7fff + ((u >> 16) & 1);   // RNE
    return (unsigned short)(u >> 16);
}

__global__ __launch_bounds__(256) void zero_ws_kernel(float4* __restrict__ ws) {
    ws[blockIdx.x * 256 + threadIdx.x] = float4{0.f, 0.f, 0.f, 0.f};
}

// Fused: per-node attention score (bf16 MFMA) + exp + segmented weighted sums.
// r14 vs r13: per-instruction-coalesced z staging. r13 had each thread read
// its own 128B row at 128B lane stride -> every global_load_dwordx4 touched
// 64 distinct cache lines (~64 cyc L1 occupancy each; ~26us/CU total). Now
// thread t, chunk q loads float4 #(q*256+t) of the block's contiguous 2048-
// float4 region (wave = 1KB contiguous, 8 lines), cvt to bf16, ds_write_b64
// into the same [node][quad] LDS slot as before. zr[32] regs freed.
__global__ __launch_bounds__(BLK, 2) void attn_seg_kernel(
    const float* __restrict__ z, const int* __restrict__ batch,
    const float* __restrict__ w1, const float* __restrict__ b1,
    const float* __restrict__ w2, const float* __restrict__ b2v,
    float* __restrict__ se, float* __restrict__ sez, int n)
{
    // layout (bytes):
    //     0 .. 20480  zb   [256][ZSTRIDE] bf16 z rows (lives whole kernel)
    // 20480 .. 21504  gls  [256] i32
    // 21504 .. 22528  ev   [256] f32
    // 22528 .. 25088  w1T  [32][ZSTRIDE] bf16 (dead after MFMA)
    //                      ALIASED by part [16][36] f32 (phase 2; col 32 = e,
    //                      col 33 = chunk-final graph id)
    // 25088 .. 26112  tab  [256] f32 (dead after alpha read)
    __shared__ __align__(16) char smem[26112];
    char*  zb   = smem;
    int*   gls  = (int*)(smem + 20480);
    float* ev   = (float*)(smem + 21504);
    char*  w1T  = smem + 22528;
    float* part = (float*)(smem + 22528);
    float* tab  = (float*)(smem + 25088);

    const int t = threadIdx.x;
    const int lane = t & 63, w = t >> 6;
    const int mrow = lane & 15, grp = lane >> 4;
    const int nd = blockIdx.x * BLK + t;
    const int ndL = (nd < n) ? nd : (n - 1);    // clamp; clamped rows get e=0
    gls[t] = batch[ndL];

    // small per-lane gathers (128B regions, L1-hot)
    const float b1a = b1[mrow], b1b = b1[mrow + 16];
    const float w2a = w2[mrow], w2b = w2[mrow + 16];

    // ---- coalesced z staging: block region = 2048 float4s; thread t, chunk q
    // loads float4 #(q*256+t) -> per-wave 1KB contiguous ----
    {
        const size_t blk_f4 = (size_t)blockIdx.x * 2048;
        const size_t max_f4 = (size_t)n * 8;
        const float4* z4 = (const float4*)z;
        float4 v4s[8];
        #pragma unroll
        for (int q = 0; q < 8; ++q) {
            size_t f = blk_f4 + q*256 + t;
            if (f >= max_f4) f = max_f4 - 1;   // last block only; finite values
            v4s[q] = z4[f];
        }
        #pragma unroll
        for (int q = 0; q < 8; ++q) {
            int lo, hi;
            asm("v_cvt_pk_bf16_f32 %0, %1, %2" : "=v"(lo) : "v"(v4s[q].x), "v"(v4s[q].y));
            asm("v_cvt_pk_bf16_f32 %0, %1, %2" : "=v"(hi) : "v"(v4s[q].z), "v"(v4s[q].w));
            const int node = q*32 + (t >> 3), quad = t & 7;
            *(int2*)(zb + node*ZSTRIDE + quad*8) = int2{lo, hi};
        }
    }

    // ---- stage W1^T as bf16: w1T[n][k], 1024 elems / 256 threads ----
    #pragma unroll
    for (int i = 0; i < 4; ++i) {
        int idx = t*4 + i, k = idx >> 5, nc = idx & 31;
        *(unsigned short*)(w1T + nc*ZSTRIDE + k*2) = f32_to_bf16(w1[k*LATENT + nc]);
    }
    __syncthreads();   // B1: z-tile + w1T + gls visible

    // ---- MFMA: per wave, 64 nodes x 32 hidden, K=32 ----
    bf16x8 A[4];
    #pragma unroll
    for (int T = 0; T < 4; ++T)
        A[T] = *(const bf16x8*)(zb + (w*64 + T*16 + mrow)*ZSTRIDE + grp*16);
    bf16x8 Bh0 = *(const bf16x8*)(w1T + mrow*ZSTRIDE + grp*16);          // hidden 0-15
    bf16x8 Bh1 = *(const bf16x8*)(w1T + (mrow+16)*ZSTRIDE + grp*16);     // hidden 16-31

    const f32x4 c0 = {b1a, b1a, b1a, b1a};
    const f32x4 c1 = {b1b, b1b, b1b, b1b};
    float p[4][4];
    #pragma unroll
    for (int T = 0; T < 4; ++T) {
        f32x4 d0 = __builtin_amdgcn_mfma_f32_16x16x32_bf16(A[T], Bh0, c0, 0, 0, 0);
        f32x4 d1 = __builtin_amdgcn_mfma_f32_16x16x32_bf16(A[T], Bh1, c1, 0, 0, 0);
        #pragma unroll
        for (int r = 0; r < 4; ++r)
            p[T][r] = tanh_fast(d0[r]) * w2a + tanh_fast(d1[r]) * w2b;
    }
    // sum the 16 lanes of each group (hidden cols); total lands in lane 15 of group
    #pragma unroll
    for (int T = 0; T < 4; ++T) {
        #pragma unroll
        for (int r = 0; r < 4; ++r) {
            float v = p[T][r];
            v = dpp_shr_add<0x111>(v);
            v = dpp_shr_add<0x112>(v);
            v = dpp_shr_add<0x114>(v);
            v = dpp_shr_add<0x118>(v);
            p[T][r] = v;
        }
    }
    if (mrow == 15) {  // lane 16*grp+15 holds sums for node-rows grp*4+r of tile T
        #pragma unroll
        for (int T = 0; T < 4; ++T)
            *(f32x4*)(tab + w*64 + T*16 + grp*4) = f32x4{p[T][0], p[T][1], p[T][2], p[T][3]};
    }
    __syncthreads();   // B2: alpha table visible

    // node n=lane: T=n>>4, g=(n>>2)&3, r=n&3
    float alpha = tab[w*64 + (lane>>4)*16 + ((lane>>2)&3)*4 + (lane&3)] + b2v[0];
    // global-max subtraction cancels in per-graph normalization; skip it.
    const float e = (nd < n) ? __expf(alpha) : 0.f;
    ev[t] = e;
    __syncthreads();   // B3: ev visible; w1T/tab reads done (part may overwrite)

    // register-batched segmented sweep: 16 chunks x 16 nodes.
    // thread (c = t>>4, kk = t&15) sums columns 2kk, 2kk+1 over its chunk.
    {
        const int c  = t >> 4;
        const int kk = t & 15;
        const int base = c * 16;
        const f32x4 e0 = *(const f32x4*)(ev + base);
        const f32x4 e1 = *(const f32x4*)(ev + base + 4);
        const f32x4 e2 = *(const f32x4*)(ev + base + 8);
        const f32x4 e3 = *(const f32x4*)(ev + base + 12);
        const i32x4 g0 = *(const i32x4*)(gls + base);
        const i32x4 g1 = *(const i32x4*)(gls + base + 4);
        const i32x4 g2 = *(const i32x4*)(gls + base + 8);
        const i32x4 g3 = *(const i32x4*)(gls + base + 12);

        float a0 = 0.f, a1 = 0.f;
        int gc = g0[0];
        #pragma unroll
        for (int j = 0; j < 16; ++j) {
            const int   gn = (j < 4) ? g0[j&3] : (j < 8) ? g1[j&3] : (j < 12) ? g2[j&3] : g3[j&3];
            const float ej = (j < 4) ? e0[j&3] : (j < 8) ? e1[j&3] : (j < 12) ? e2[j&3] : e3[j&3];
            const int d = *(const int*)(zb + (base + j)*ZSTRIDE + kk*4);
            if (gn != gc) {   // rare: graph boundary inside chunk
                atomicAdd(&sez[gc*LATENT + 2*kk],     a0);
                atomicAdd(&sez[gc*LATENT + 2*kk + 1], a1);
                a0 = a1 = 0.f; gc = gn;
            }
            a0 = fmaf(ej, __int_as_float((unsigned)d << 16),        a0);
            a1 = fmaf(ej, __int_as_float((unsigned)d & 0xffff0000u), a1);
        }
        *(float2*)(part + c*36 + 2*kk) = float2{a0, a1};

        if (kk == 0) {   // e-column sweep for chunk c, straight from registers
            float ae = 0.f;
            int ge = g0[0];
            #pragma unroll
            for (int j = 0; j < 16; ++j) {
                const int   gn = (j < 4) ? g0[j&3] : (j < 8) ? g1[j&3] : (j < 12) ? g2[j&3] : g3[j&3];
                const float ej = (j < 4) ? e0[j&3] : (j < 8) ? e1[j&3] : (j < 12) ? e2[j&3] : e3[j&3];
                if (gn != ge) { atomicAdd(&se[ge], ae); ae = 0.f; ge = gn; }
                ae += ej;
            }
            part[c*36 + 32] = ae;
            ((int*)part)[c*36 + 33] = g3[3];   // chunk-final graph id
        }
    }
    __syncthreads();   // B4: part staged

    // combine 16 chunk partials per column -> ~1 atomic per column per block
    if (t < 33) {
        const int col = t;               // 32 = e column
        float acc = part[col];           // chunk 0
        int gc = ((const int*)part)[33];
        #pragma unroll
        for (int cc = 1; cc < 16; ++cc) {
            const int gn = ((const int*)part)[cc*36 + 33];
            if (gn != gc) {
                if (col < 32) atomicAdd(&sez[gc*LATENT + col], acc);
                else          atomicAdd(&se[gc], acc);
                acc = 0.f; gc = gn;
            }
            acc += part[cc*36 + col];
        }
        if (col < 32) atomicAdd(&sez[gc*LATENT + col], acc);
        else          atomicAdd(&se[gc], acc);
    }
}

// One wave per graph: graph_z = sez/(se+1e-8); 32->128->64->1 MLP with sigmoid.
__global__ __launch_bounds__(64) void mlp_kernel(
    const float* __restrict__ se, const float* __restrict__ sez,
    const float* __restrict__ m1w, const float* __restrict__ m1b,
    const float* __restrict__ m2w, const float* __restrict__ m2b,
    const float* __restrict__ m3w, const float* __restrict__ m3b,
    float* __restrict__ out)
{
    int gidx = blockIdx.x;
    int lane = threadIdx.x;
    float inv = 1.f / (se[gidx] + 1e-8f);
    float gz = (lane < LATENT) ? sez[gidx*LATENT + lane] * inv : 0.f;

    float a0 = m1b[lane], a1 = m1b[lane + 64];
    #pragma unroll
    for (int k = 0; k < LATENT; ++k) {
        float zk = __shfl(gz, k);
        a0 = fmaf(zk, m1w[k*128 + lane], a0);
        a1 = fmaf(zk, m1w[k*128 + lane + 64], a1);
    }
    a0 = fmaxf(a0, 0.f); a1 = fmaxf(a1, 0.f);

    float b = m2b[lane];
    #pragma unroll
    for (int k = 0; k < 64; ++k) {
        float xk = __shfl(a0, k);
        b = fmaf(xk, m2w[k*64 + lane], b);
    }
    #pragma unroll
    for (int k = 0; k < 64; ++k) {
        float xk = __shfl(a1, k);
        b = fmaf(xk, m2w[(k+64)*64 + lane], b);
    }
    b = fmaxf(b, 0.f);

    float p = b * m3w[lane];
    #pragma unroll
    for (int s = 32; s >= 1; s >>= 1)
        p += __shfl_xor(p, s);
    if (lane == 0)
        out[gidx] = 1.f / (1.f + __expf(-(p + m3b[0])));
}

extern "C" void kernel_launch(void* const* d_in, const int* in_sizes, int n_in,
                              void* d_out, int out_size, void* d_ws, size_t ws_size,
                              hipStream_t stream)
{
    const float* z    = (const float*)d_in[0];
    const int*   batch= (const int*)d_in[1];
    const float* aw1  = (const float*)d_in[2];
    const float* ab1  = (const float*)d_in[3];
    const float* aw2  = (const float*)d_in[4];
    const float* ab2  = (const float*)d_in[5];
    const float* m1w  = (const float*)d_in[6];
    const float* m1b  = (const float*)d_in[7];
    const float* m2w  = (const float*)d_in[8];
    const float* m2b  = (const float*)d_in[9];
    const float* m3w  = (const float*)d_in[10];
    const float* m3b  = (const float*)d_in[11];
    float* out = (float*)d_out;

    int n = in_sizes[0] / LATENT;   // 2,000,000 nodes

    float* se  = (float*)d_ws;          // [4096]
    float* sez = se + N_GRAPHS;         // [4096][32]

    // N_GRAPHS*33 floats = 135168 floats = 33792 float4 = 132 blocks * 256
    zero_ws_kernel<<<132, 256, 0, stream>>>((float4*)d_ws);

    int blocks = (n + BLK - 1) / BLK;
    attn_seg_kernel<<<blocks, BLK, 0, stream>>>(z, batch, aw1, ab1, aw2, ab2, se, sez, n);
    mlp_kernel<<<N_GRAPHS, 64, 0, stream>>>(se, sez, m1w, m1b, m2w, m2b, m3w, m3b, out);
}